// Round 2
// baseline (94.513 us; speedup 1.0000x reference)
//
#include <hip/hip_runtime.h>
#include <math.h>

// Problem constants (fixed by setup_inputs)
constexpr int B       = 2;
constexpr int N       = 32768;
constexpr int D       = 3;
constexpr int M_FULL  = 8192;
constexpr int SUBDIV  = 8;
constexpr int M       = M_FULL / SUBDIV;   // 1024 subsampled verts
constexpr int NPAIR   = B * D;             // 6 independent (b,d) problems
constexpr float K4    = 5.770780163555852f; // 4*log2(e):  e^{4t} = 2^{K4*t}

// Workspace layout (floats), per pair p in [0,6):
//   arr 0: sorted keys (dv)            ws + (0*NPAIR+p)*M
//   arr 1: prefA incl prefix of mv*e^{4v}
//   arr 2: prefS incl prefix of e^{4v}
//   arr 3: sufA  incl suffix of mv*e^{-4v}
//   arr 4: sufS  incl suffix of e^{-4v}
//   arr 5: sorted vals (mv)  (K1 -> K2 only)
// total 6*6*1024*4 B = 144 KB

// ---------------- K1: rank-by-count sort ----------------
// 16 blocks x 64 threads per pair; each thread ranks one vert against all
// 1024 keys staged in LDS (float4 broadcast reads), scatters (key,val) to
// its sorted slot in ws. Ranks are a permutation -> no write races.
__global__ __launch_bounds__(64) void k_rank(const float* __restrict__ dv,
                                             const float* __restrict__ mv,
                                             float* __restrict__ ws)
{
    __shared__ __align__(16) float sKey[M];
    const int p = blockIdx.x >> 4;      // pair
    const int q = blockIdx.x & 15;      // quarter-of-16
    const int b = p / 3, d = p % 3;
    const int tid = threadIdx.x;

    for (int i = tid; i < M; i += 64)
        sKey[i] = dv[(b * M_FULL + i * SUBDIV) * D + d];
    const int myIdx = q * 64 + tid;
    const float myVal = mv[(b * M_FULL + myIdx * SUBDIV) * D + d];
    __syncthreads();
    const float myKey = sKey[myIdx];

    int rank = 0;
    #pragma unroll 4
    for (int j = 0; j < M; j += 4) {
        const float4 kk = *reinterpret_cast<const float4*>(sKey + j);
        rank += (kk.x < myKey) || (kk.x == myKey && (j + 0) < myIdx);
        rank += (kk.y < myKey) || (kk.y == myKey && (j + 1) < myIdx);
        rank += (kk.z < myKey) || (kk.z == myKey && (j + 2) < myIdx);
        rank += (kk.w < myKey) || (kk.w == myKey && (j + 3) < myIdx);
    }
    ws[(0 * NPAIR + p) * M + rank] = myKey;
    ws[(5 * NPAIR + p) * M + rank] = myVal;
}

// ---------------- K2: build prefix/suffix tables ----------------
// One 1024-thread block per pair. Inclusive scans via wave shuffle (6 steps)
// + cross-wave partial accumulation. Suffix scans run on the reversed index.
__global__ __launch_bounds__(1024) void k_scan(float* __restrict__ ws)
{
    __shared__ float part[4][16];
    const int p = blockIdx.x;
    const int tid = threadIdx.x;
    const int lane = tid & 63, wid = tid >> 6;
    const float* key = ws + (0 * NPAIR + p) * M;
    const float* val = ws + (5 * NPAIR + p) * M;

    const int r = M - 1 - tid;
    const float kf = key[tid], vf = val[tid];
    const float kr = key[r],   vr = val[r];

    const float ef  = __builtin_amdgcn_exp2f( K4 * kf);   // e^{4v}
    const float er  = __builtin_amdgcn_exp2f(-K4 * kr);   // e^{-4v} (reversed idx)
    float tA  = vf * ef;   // -> prefA
    float tS  = ef;        // -> prefS
    float tAr = vr * er;   // -> sufA (reversed)
    float tSr = er;        // -> sufS (reversed)

    #pragma unroll
    for (int off = 1; off < 64; off <<= 1) {
        const float a = __shfl_up(tA,  off, 64);
        const float s = __shfl_up(tS,  off, 64);
        const float ar = __shfl_up(tAr, off, 64);
        const float sr = __shfl_up(tSr, off, 64);
        if (lane >= off) { tA += a; tS += s; tAr += ar; tSr += sr; }
    }
    if (lane == 63) {
        part[0][wid] = tA; part[1][wid] = tS;
        part[2][wid] = tAr; part[3][wid] = tSr;
    }
    __syncthreads();
    float oA = 0.f, oS = 0.f, oAr = 0.f, oSr = 0.f;
    for (int w = 0; w < wid; ++w) {
        oA += part[0][w]; oS += part[1][w];
        oAr += part[2][w]; oSr += part[3][w];
    }
    ws[(1 * NPAIR + p) * M + tid] = tA + oA;
    ws[(2 * NPAIR + p) * M + tid] = tS + oS;
    ws[(3 * NPAIR + p) * M + r]   = tAr + oAr;
    ws[(4 * NPAIR + p) * M + r]   = tSr + oSr;
}

// ---------------- K3: main lookup kernel ----------------
// out = (e^{-4x}*prefA[k-1] + e^{4x}*sufA[k]) / (e^{-4x}*prefS[k-1] + e^{4x}*sufS[k])
// with k = #{sorted keys <= x} found by branchless binary search in LDS.
constexpr int CHUNKS = N / 256;   // 128 blocks per pair

__global__ __launch_bounds__(256) void k_main(const float* __restrict__ x,
                                              const float* __restrict__ ws,
                                              float* __restrict__ out)
{
    __shared__ __align__(16) float sKey[M + 4];  // +sentinel (padded for b128)
    __shared__ __align__(16) float sPA[M], sPS[M], sSA[M], sSS[M];
    const int p = blockIdx.x >> 7;
    const int c = blockIdx.x & 127;
    const int b = p / 3, d = p % 3;
    const int tid = threadIdx.x;

    const int i4 = tid * 4;
    *reinterpret_cast<float4*>(sKey + i4) =
        *reinterpret_cast<const float4*>(ws + (0 * NPAIR + p) * M + i4);
    *reinterpret_cast<float4*>(sPA + i4) =
        *reinterpret_cast<const float4*>(ws + (1 * NPAIR + p) * M + i4);
    *reinterpret_cast<float4*>(sPS + i4) =
        *reinterpret_cast<const float4*>(ws + (2 * NPAIR + p) * M + i4);
    *reinterpret_cast<float4*>(sSA + i4) =
        *reinterpret_cast<const float4*>(ws + (3 * NPAIR + p) * M + i4);
    *reinterpret_cast<float4*>(sSS + i4) =
        *reinterpret_cast<const float4*>(ws + (4 * NPAIR + p) * M + i4);
    if (tid == 0) sKey[M] = INFINITY;
    __syncthreads();

    const int n = c * 256 + tid;
    const int o = (b * N + n) * D + d;
    const float xv = x[o];

    // k = count of keys <= xv; 11 iterations converge for size 1024,
    // sKey[1024] = +inf keeps the read in-bounds when lo==hi==1024.
    int lo = 0, hi = M;
    #pragma unroll
    for (int it = 0; it < 11; ++it) {
        const int mid = (lo + hi) >> 1;
        const bool cnd = sKey[mid] <= xv;
        lo = cnd ? mid + 1 : lo;
        hi = cnd ? hi : mid;
    }
    const int k = lo;

    const float en = __builtin_amdgcn_exp2f(-K4 * xv);  // e^{-4x}
    const float ep = __builtin_amdgcn_exp2f( K4 * xv);  // e^{+4x}
    const float pA = k ? sPA[k - 1] : 0.f;
    const float pS = k ? sPS[k - 1] : 0.f;
    const float sA = (k < M) ? sSA[k] : 0.f;
    const float sS = (k < M) ? sSS[k] : 0.f;
    out[o] = (en * pA + ep * sA) / (en * pS + ep * sS);
}

extern "C" void kernel_launch(void* const* d_in, const int* in_sizes, int n_in,
                              void* d_out, int out_size, void* d_ws, size_t ws_size,
                              hipStream_t stream) {
    const float* x  = (const float*)d_in[0];
    const float* dv = (const float*)d_in[1];
    const float* mv = (const float*)d_in[2];
    float* out = (float*)d_out;
    float* ws  = (float*)d_ws;   // needs 144 KB

    k_rank<<<NPAIR * 16, 64, 0, stream>>>(dv, mv, ws);
    k_scan<<<NPAIR, 1024, 0, stream>>>(ws);
    k_main<<<NPAIR * CHUNKS, 256, 0, stream>>>(x, ws, out);
}

// Round 4
// 79.189 us; speedup vs baseline: 1.1935x; 1.1935x over previous
//
#include <hip/hip_runtime.h>
#include <math.h>

// Problem constants (fixed by setup_inputs)
constexpr int B       = 2;
constexpr int N       = 32768;
constexpr int D       = 3;
constexpr int M_FULL  = 8192;
constexpr int SUBDIV  = 8;
constexpr int M       = M_FULL / SUBDIV;   // 1024 subsampled verts per (b,d)
constexpr int K       = 512;               // value buckets over [-4,4]
constexpr float LO    = -4.0f;
constexpr float INV_W = 64.0f;             // 1 / (8/512)
constexpr int BLOCK   = 256;
constexpr int CHUNKS  = N / BLOCK;         // 128 blocks per (b,d) pair
constexpr float K4    = 5.770780163555852f; // 4*log2(e): e^{4t} = 2^{K4*t}

// 512-element wave-parallel EXCLUSIVE prefix scan (one wave, lane owns 8 slots).
// Accumulates low-index-first: small exp terms first -> good numerics.
__device__ inline void scan512_pre(float* a) {
    const int lane = threadIdx.x & 63;
    const int base = lane * 8;
    float xv[8], e[8];
    float ls = 0.f;
    #pragma unroll
    for (int t = 0; t < 8; ++t) xv[t] = a[base + t];
    #pragma unroll
    for (int t = 0; t < 8; ++t) { e[t] = ls; ls += xv[t]; }
    float inc = ls;
    #pragma unroll
    for (int off = 1; off < 64; off <<= 1) {
        const float tmp = __shfl_up(inc, off, 64);
        if (lane >= off) inc += tmp;
    }
    const float exoff = inc - ls;   // sum of lanes strictly below (their own totals)
    #pragma unroll
    for (int t = 0; t < 8; ++t) a[base + t] = exoff + e[t];
}

// 512-element wave-parallel INCLUSIVE suffix scan: a[i] <- sum_{t>=i} a[t].
// Accumulates high-index-first (tiny e^{-4v} terms first) -> no cancellation.
__device__ inline void scan512_suf(float* a) {
    const int lane = threadIdx.x & 63;
    const int base = lane * 8;
    float xv[8], e[8];
    float ls = 0.f;
    #pragma unroll
    for (int t = 0; t < 8; ++t) xv[t] = a[base + t];
    #pragma unroll
    for (int t = 7; t >= 0; --t) { e[t] = ls; ls += xv[t]; }  // right-exclusive in-lane
    float inc = ls;
    #pragma unroll
    for (int off = 1; off < 64; off <<= 1) {
        const float tmp = __shfl_down(inc, off, 64);
        if (lane + off < 64) inc += tmp;
    }
    const float exoff = inc - ls;   // sum of lanes strictly above
    #pragma unroll
    for (int t = 0; t < 8; ++t) a[base + t] = exoff + e[t] + xv[t];
}

__device__ inline void scan512_i(const int* cntA, int* begA, int* curA) {
    const int lane = threadIdx.x & 63;
    const int base = lane * 8;
    int xv[8], e[8];
    int ls = 0;
    #pragma unroll
    for (int t = 0; t < 8; ++t) xv[t] = cntA[base + t];
    #pragma unroll
    for (int t = 0; t < 8; ++t) { e[t] = ls; ls += xv[t]; }
    int inc = ls;
    #pragma unroll
    for (int off = 1; off < 64; off <<= 1) {
        const int tmp = __shfl_up(inc, off, 64);
        if (lane >= off) inc += tmp;
    }
    const int exoff = inc - ls;
    #pragma unroll
    for (int t = 0; t < 8; ++t) {
        begA[base + t] = exoff + e[t];
        curA[base + t] = exoff + e[t];
    }
}

__global__ __launch_bounds__(BLOCK) void deformer_one(
    const float* __restrict__ x,
    const float* __restrict__ dverts,
    const float* __restrict__ mverts,
    float* __restrict__ out)
{
    // bucket-grouped per-vert tuples
    __shared__ float sV[M], sAp[M], sSp[M], sAm[M], sSm[M];      // 20 KB
    // per-bucket aggregates; after scans: Ap/Sp = exclusive prefix,
    // Am/Sm = inclusive suffix.
    __shared__ float gAp[K], gSp[K], gAm[K], gSm[K];             // 8 KB
    __shared__ int   cnt[K], beg[K], cur[K];                      // 6 KB

    const int tid = threadIdx.x;
    const int p = blockIdx.x >> 7;    // pair 0..5
    const int c = blockIdx.x & 127;   // chunk within pair
    const int b = p / 3, d = p % 3;

    for (int i = tid; i < K; i += BLOCK) {
        cnt[i] = 0; gAp[i] = 0.f; gSp[i] = 0.f; gAm[i] = 0.f; gSm[i] = 0.f;
    }
    __syncthreads();

    // Build: 4 verts/thread. Tuples stay in registers until scatter.
    float vv[4], ap[4], sp[4], am[4], sm[4]; int bj[4];
    #pragma unroll
    for (int u = 0; u < 4; ++u) {
        const int i = tid + u * BLOCK;
        const int g = (b * M_FULL + i * SUBDIV) * D + d;
        const float v = dverts[g];
        const float w = mverts[g];
        const float epv = __builtin_amdgcn_exp2f( K4 * v);   // e^{4v}
        const float emv = __builtin_amdgcn_exp2f(-K4 * v);   // e^{-4v}
        vv[u] = v;
        ap[u] = w * epv; sp[u] = epv;
        am[u] = w * emv; sm[u] = emv;
        int j = (int)floorf((v - LO) * INV_W);
        j = j < 0 ? 0 : (j > K - 1 ? K - 1 : j);
        bj[u] = j;
        atomicAdd(&cnt[j], 1);
        atomicAdd(&gAp[j], ap[u]);
        atomicAdd(&gSp[j], sp[u]);
        atomicAdd(&gAm[j], am[u]);
        atomicAdd(&gSm[j], sm[u]);
    }
    __syncthreads();

    // Scans: 4 waves cover 5 scans (wave 0 does two disjoint ones).
    const int wid = tid >> 6;
    if (wid == 0) { scan512_i(cnt, beg, cur); scan512_suf(gSm); }
    else if (wid == 1) scan512_pre(gAp);
    else if (wid == 2) scan512_pre(gSp);
    else               scan512_suf(gAm);
    __syncthreads();

    // Counting scatter into bucket-grouped order.
    #pragma unroll
    for (int u = 0; u < 4; ++u) {
        const int pos = atomicAdd(&cur[bj[u]], 1);
        sV[pos] = vv[u]; sAp[pos] = ap[u]; sSp[pos] = sp[u];
        sAm[pos] = am[u]; sSm[pos] = sm[u];
    }
    __syncthreads();

    // Query phase: one output element per thread.
    const int n = c * BLOCK + tid;
    const int o = (b * N + n) * D + d;
    const float xq = x[o];

    int j = (int)floorf((xq - LO) * INV_W);
    j = j < 0 ? 0 : (j > K - 1 ? K - 1 : j);

    const float en  = __builtin_amdgcn_exp2f(-K4 * xq);  // e^{-4x}
    const float epx = __builtin_amdgcn_exp2f( K4 * xq);  // e^{+4x}

    float Ap = gAp[j];                          // buckets strictly below j
    float Sp = gSp[j];
    float Am = (j < K - 1) ? gAm[j + 1] : 0.f;  // buckets strictly above j
    float Sm = (j < K - 1) ? gSm[j + 1] : 0.f;

    const int s0 = beg[j], s1 = s0 + cnt[j];
    float rAp = 0.f, rSp = 0.f, rAm = 0.f, rSm = 0.f;
    for (int i = s0; i < s1; ++i) {
        const bool le = (sV[i] <= xq);
        rAp += le ? sAp[i] : 0.f;
        rSp += le ? sSp[i] : 0.f;
        rAm += le ? 0.f : sAm[i];
        rSm += le ? 0.f : sSm[i];
    }
    out[o] = (en * (Ap + rAp) + epx * (Am + rAm)) /
             (en * (Sp + rSp) + epx * (Sm + rSm));
}

extern "C" void kernel_launch(void* const* d_in, const int* in_sizes, int n_in,
                              void* d_out, int out_size, void* d_ws, size_t ws_size,
                              hipStream_t stream) {
    const float* x  = (const float*)d_in[0];
    const float* dv = (const float*)d_in[1];
    const float* mv = (const float*)d_in[2];
    float* out = (float*)d_out;

    deformer_one<<<B * D * CHUNKS, BLOCK, 0, stream>>>(x, dv, mv, out);
}